// Round 3
// baseline (48.940 us; speedup 1.0000x reference)
//
#include <hip/hip_runtime.h>

#define NB 32
#define NP 32
#define NS 512
#define NPS (NP * NS)   // 16384

typedef float f32x4 __attribute__((ext_vector_type(4)));  // clang vector: OK for nontemporal builtins

// ---------------------------------------------------------------------------
// Fully fused: for each (b, p, j) compute
//   point[b,j]  = quat_rotate(qn[b,owner], (2*coef-1)*shape[owner]) + trans[owner]
//   p_loc       = quat_rotate(conj(qn[b,p]), point - trans[p])
//   tsdfOut     = sum(relu(shape[p]-|p_loc|)^2) * iou[p] * (owner!=p)
//   weight      = prod(shape[owner]) * iou[owner]
//   tsdfGT      = 0
// 256 threads/block, 4 j per thread -> 1024 j per block (one owner pair);
// grid = B*P*16 = 16384 blocks. Forward points are recomputed per p (32x):
// the redundant coef reads are L2-served (196 KB per b), the redundant VALU
// is free (kernel is write-BW-bound). Nontemporal stores keep the 201 MB of
// streaming output from evicting coef in L2.
// ---------------------------------------------------------------------------
__global__ void __launch_bounds__(256)
fused_tsdf_kernel(const float* __restrict__ shape,   // (B,P,3)
                  const float* __restrict__ trans,   // (B,P,3)
                  const float* __restrict__ quat,    // (B,P,4)
                  const float* __restrict__ iou,     // (B,P)
                  const float* __restrict__ coef,    // (B,P,S,3)
                  float* __restrict__ out)           // tsdfOut | weight | tsdfGT
{
    const size_t TOT = (size_t)NB * NP * NPS;

    int blk   = blockIdx.x;
    int chunk = blk & 15;          // 16 chunks of 1024 j
    int bp    = blk >> 4;
    int b     = bp >> 5;
    int p     = bp & 31;
    int j0    = chunk * 1024 + threadIdx.x * 4;
    int owner = j0 >> 9;           // same owner for all 4 j (j0 % 512 <= 508)
    int bo    = b * NP + owner;

    // ---- owner (forward) parameters ----
    const float* qo = quat + (size_t)bo * 4;
    float ow = qo[0], oqx = qo[1], oqy = qo[2], oqz = qo[3];
    float oinv = 1.0f / sqrtf(ow*ow + oqx*oqx + oqy*oqy + oqz*oqz);
    ow *= oinv; oqx *= oinv; oqy *= oinv; oqz *= oinv;
    const float* sho = shape + (size_t)bo * 3;
    float osx = sho[0], osy = sho[1], osz = sho[2];
    const float* tro = trans + (size_t)bo * 3;
    float otx = tro[0], oty = tro[1], otz = tro[2];
    float wval = osx * osy * osz * iou[bo];

    // ---- p (inverse / conjugate) parameters ----
    const float* q = quat + (size_t)bp * 4;
    float qw = q[0], qx = q[1], qy = q[2], qz = q[3];
    float inv = 1.0f / sqrtf(qw*qw + qx*qx + qy*qy + qz*qz);
    qw *= inv; qx *= -inv; qy *= -inv; qz *= -inv;
    const float* sh = shape + (size_t)bp * 3;
    float sx = sh[0], sy = sh[1], sz = sh[2];
    const float* tr = trans + (size_t)bp * 3;
    float tx = tr[0], ty = tr[1], tz = tr[2];
    float scale = iou[bp] * ((owner != p) ? 1.0f : 0.0f);

    // ---- coef for 4 consecutive points: 12 floats = 3 aligned float4 ----
    const f32x4* c4 = (const f32x4*)(coef + ((size_t)bo * NS + (j0 & (NS - 1))) * 3);
    f32x4 ca = c4[0], cb = c4[1], cc = c4[2];
    float cf[12] = {ca.x, ca.y, ca.z, ca.w,
                    cb.x, cb.y, cb.z, cb.w,
                    cc.x, cc.y, cc.z, cc.w};

    f32x4 res;
    #pragma unroll
    for (int k = 0; k < 4; ++k) {
        // local point in owner frame
        float vx = (2.0f * cf[3*k+0] - 1.0f) * osx;
        float vy = (2.0f * cf[3*k+1] - 1.0f) * osy;
        float vz = (2.0f * cf[3*k+2] - 1.0f) * osz;
        // forward rotate by owner quat
        float ux = oqy*vz - oqz*vy;
        float uy = oqz*vx - oqx*vz;
        float uz = oqx*vy - oqy*vx;
        float uux = oqy*uz - oqz*uy;
        float uuy = oqz*ux - oqx*uz;
        float uuz = oqx*uy - oqy*ux;
        float px = vx + 2.0f*(ow*ux + uux) + otx;
        float py = vy + 2.0f*(ow*uy + uuy) + oty;
        float pz = vz + 2.0f*(ow*uz + uuz) + otz;
        // relative to p, inverse-rotate (conjugate quat)
        float rx = px - tx, ry = py - ty, rz = pz - tz;
        float vx2 = qy*rz - qz*ry;
        float vy2 = qz*rx - qx*rz;
        float vz2 = qx*ry - qy*rx;
        float wx2 = qy*vz2 - qz*vy2;
        float wy2 = qz*vx2 - qx*vz2;
        float wz2 = qx*vy2 - qy*vx2;
        float lx = rx + 2.0f*(qw*vx2 + wx2);
        float ly = ry + 2.0f*(qw*vy2 + wy2);
        float lz = rz + 2.0f*(qw*vz2 + wz2);
        float ppx = fmaxf(sx - fabsf(lx), 0.0f);
        float ppy = fmaxf(sy - fabsf(ly), 0.0f);
        float ppz = fmaxf(sz - fabsf(lz), 0.0f);
        res[k] = (ppx*ppx + ppy*ppy + ppz*ppz) * scale;
    }

    size_t base = (size_t)bp * NPS + j0;
    f32x4 wv = {wval, wval, wval, wval};
    f32x4 zv = {0.0f, 0.0f, 0.0f, 0.0f};
    __builtin_nontemporal_store(res, (f32x4*)(out + base));
    __builtin_nontemporal_store(wv,  (f32x4*)(out + TOT + base));
    __builtin_nontemporal_store(zv,  (f32x4*)(out + 2 * TOT + base));
}

extern "C" void kernel_launch(void* const* d_in, const int* in_sizes, int n_in,
                              void* d_out, int out_size, void* d_ws, size_t ws_size,
                              hipStream_t stream) {
    const float* shape = (const float*)d_in[0];   // (B,P,3)
    const float* trans = (const float*)d_in[1];   // (B,P,3)
    const float* quat  = (const float*)d_in[2];   // (B,P,4)
    const float* iou   = (const float*)d_in[3];   // (B,P)
    const float* coef  = (const float*)d_in[4];   // (B,P,S,3)
    float* out = (float*)d_out;

    int nblocks = NB * NP * 16;                   // 16384
    fused_tsdf_kernel<<<nblocks, 256, 0, stream>>>(shape, trans, quat, iou, coef, out);
}

// Round 4
// 34.913 us; speedup vs baseline: 1.4018x; 1.4018x over previous
//
#include <hip/hip_runtime.h>

#define NB 32
#define NP 32
#define NS 512
#define NPS (NP * NS)   // 16384

typedef float f32x4 __attribute__((ext_vector_type(4)));

// ---------------------------------------------------------------------------
// One block = one (b, chunk of 1024 j). 256 threads x 4 j each.
// Phase 1: threads 0..31 stage per-p params into LDS (normalized quat, shape,
//          trans, iou, vol).
// Phase 2: each thread computes its 4 forward points ONCE (coef read exactly
//          once from HBM, kept in registers).
// Phase 3: loop p = 0..31: inverse-rotate the 4 points into p's frame, write
//          tsdfOut / weight / tsdfGT as three coalesced float4 streams.
// Traffic: 201 MB stores + 6 MB coef reads -> write-BW-bound (~30 us ideal).
// Plain stores (nontemporal regressed in R3).
// ---------------------------------------------------------------------------
__global__ void __launch_bounds__(256)
fused_all_p_kernel(const float* __restrict__ shape,   // (B,P,3)
                   const float* __restrict__ trans,   // (B,P,3)
                   const float* __restrict__ quat,    // (B,P,4)
                   const float* __restrict__ iou,     // (B,P)
                   const float* __restrict__ coef,    // (B,P,S,3)
                   float* __restrict__ out)           // tsdfOut | weight | tsdfGT
{
    const size_t TOT = (size_t)NB * NP * NPS;

    // per-p params: qw,qx,qy,qz (normalized), sx,sy,sz, tx,ty,tz, iou, vol
    __shared__ float sP[NP][12];

    int blk   = blockIdx.x;
    int b     = blk >> 4;
    int chunk = blk & 15;
    int tid   = threadIdx.x;

    if (tid < NP) {
        int p  = tid;
        int bp = b * NP + p;
        const float* q = quat + (size_t)bp * 4;
        float qw = q[0], qx = q[1], qy = q[2], qz = q[3];
        float inv = 1.0f / sqrtf(qw*qw + qx*qx + qy*qy + qz*qz);
        sP[p][0] = qw * inv; sP[p][1] = qx * inv;
        sP[p][2] = qy * inv; sP[p][3] = qz * inv;
        const float* sh = shape + (size_t)bp * 3;
        sP[p][4] = sh[0]; sP[p][5] = sh[1]; sP[p][6] = sh[2];
        const float* tr = trans + (size_t)bp * 3;
        sP[p][7] = tr[0]; sP[p][8] = tr[1]; sP[p][9] = tr[2];
        float io = iou[bp];
        sP[p][10] = io;
        sP[p][11] = sh[0] * sh[1] * sh[2] * io;   // vol * iou
    }
    __syncthreads();

    int j0    = chunk * 1024 + tid * 4;
    int owner = j0 >> 9;            // constant for the thread's 4 j
    int js    = j0 & (NS - 1);

    // ---- owner (forward) params from LDS broadcast ----
    float ow  = sP[owner][0], oqx = sP[owner][1], oqy = sP[owner][2], oqz = sP[owner][3];
    float osx = sP[owner][4], osy = sP[owner][5], osz = sP[owner][6];
    float otx = sP[owner][7], oty = sP[owner][8], otz = sP[owner][9];
    float wval = sP[owner][11];

    // ---- coef: 12 floats = 3 aligned float4 ----
    const f32x4* c4 = (const f32x4*)(coef + ((size_t)(b * NP + owner) * NS + js) * 3);
    f32x4 ca = c4[0], cb = c4[1], cc = c4[2];
    float cf[12] = {ca.x, ca.y, ca.z, ca.w,
                    cb.x, cb.y, cb.z, cb.w,
                    cc.x, cc.y, cc.z, cc.w};

    // ---- forward points, computed once, kept in registers ----
    float fx[4], fy[4], fz[4];
    #pragma unroll
    for (int k = 0; k < 4; ++k) {
        float vx = (2.0f * cf[3*k+0] - 1.0f) * osx;
        float vy = (2.0f * cf[3*k+1] - 1.0f) * osy;
        float vz = (2.0f * cf[3*k+2] - 1.0f) * osz;
        float ux = oqy*vz - oqz*vy;
        float uy = oqz*vx - oqx*vz;
        float uz = oqx*vy - oqy*vx;
        float uux = oqy*uz - oqz*uy;
        float uuy = oqz*ux - oqx*uz;
        float uuz = oqx*uy - oqy*ux;
        fx[k] = vx + 2.0f*(ow*ux + uux) + otx;
        fy[k] = vy + 2.0f*(ow*uy + uuy) + oty;
        fz[k] = vz + 2.0f*(ow*uz + uuz) + otz;
    }

    f32x4 wv = {wval, wval, wval, wval};
    f32x4 zv = {0.0f, 0.0f, 0.0f, 0.0f};

    size_t base = (size_t)(b * NP) * NPS + j0;   // p = 0
    for (int p = 0; p < NP; ++p, base += NPS) {
        // conjugate of normalized quat
        float qw =  sP[p][0];
        float qx = -sP[p][1];
        float qy = -sP[p][2];
        float qz = -sP[p][3];
        float sx = sP[p][4], sy = sP[p][5], sz = sP[p][6];
        float tx = sP[p][7], ty = sP[p][8], tz = sP[p][9];
        float scale = sP[p][10] * ((owner != p) ? 1.0f : 0.0f);

        f32x4 res;
        #pragma unroll
        for (int k = 0; k < 4; ++k) {
            float rx = fx[k] - tx, ry = fy[k] - ty, rz = fz[k] - tz;
            float ux = qy*rz - qz*ry;
            float uy = qz*rx - qx*rz;
            float uz = qx*ry - qy*rx;
            float uux = qy*uz - qz*uy;
            float uuy = qz*ux - qx*uz;
            float uuz = qx*uy - qy*ux;
            float lx = rx + 2.0f*(qw*ux + uux);
            float ly = ry + 2.0f*(qw*uy + uuy);
            float lz = rz + 2.0f*(qw*uz + uuz);
            float px_ = fmaxf(sx - fabsf(lx), 0.0f);
            float py_ = fmaxf(sy - fabsf(ly), 0.0f);
            float pz_ = fmaxf(sz - fabsf(lz), 0.0f);
            res[k] = (px_*px_ + py_*py_ + pz_*pz_) * scale;
        }

        *(f32x4*)(out + base)           = res;
        *(f32x4*)(out + TOT + base)     = wv;
        *(f32x4*)(out + 2 * TOT + base) = zv;
    }
}

extern "C" void kernel_launch(void* const* d_in, const int* in_sizes, int n_in,
                              void* d_out, int out_size, void* d_ws, size_t ws_size,
                              hipStream_t stream) {
    const float* shape = (const float*)d_in[0];   // (B,P,3)
    const float* trans = (const float*)d_in[1];   // (B,P,3)
    const float* quat  = (const float*)d_in[2];   // (B,P,4)
    const float* iou   = (const float*)d_in[3];   // (B,P)
    const float* coef  = (const float*)d_in[4];   // (B,P,S,3)
    float* out = (float*)d_out;

    int nblocks = NB * 16;                        // 512 blocks: (b, j-chunk)
    fused_all_p_kernel<<<nblocks, 256, 0, stream>>>(shape, trans, quat, iou, coef, out);
}